// Round 16
// baseline (178.473 us; speedup 1.0000x reference)
//
#include <hip/hip_runtime.h>
#include <stdint.h>
#include <stddef.h>

#define NB 8
#define NC 512
#define NL 64
#define NN 6272
#define NT 64
#define NTILES (NN / NT)    // 98
#define NTA 32              // kA/kP sub-tile width (n)
#define NTILES32 (NN / NTA) // 196
#define NCHUNK 14
#define NSUB (NTILES32 / NCHUNK)  // 14

typedef short bf16x8 __attribute__((ext_vector_type(8)));
typedef float f32x4 __attribute__((ext_vector_type(4)));

__device__ __forceinline__ unsigned short f2bf(float f) {
    uint32_t u = __float_as_uint(f);
    u += 0x7fffu + ((u >> 16) & 1u);
    return (unsigned short)(u >> 16);
}
__device__ __forceinline__ float bf2f(unsigned short s) {
    return __uint_as_float(((uint32_t)s) << 16);
}

// ---------------------------------------------------------------------------
// Kernel W: repack 64x512 f32 weights into fragment-ordered bf16.
// ---------------------------------------------------------------------------
__global__ __launch_bounds__(512)
void kW(const float* __restrict__ w0, const float* __restrict__ w1,
        unsigned short* __restrict__ f0, unsigned short* __restrict__ f1) {
    const float* src = blockIdx.x ? w1 : w0;
    unsigned short* dst = blockIdx.x ? f1 : f0;
    int t = threadIdx.x;
    #pragma unroll
    for (int j = 0; j < 8; j++) {
        int chunk = t + j * 512;
        int r = chunk & 15, q = (chunk >> 4) & 3, it = (chunk >> 6) & 15, lg = chunk >> 10;
        const float* sp = src + (size_t)(lg * 16 + r) * NC + it * 32 + q * 8;
        float4 x = *(const float4*)sp;
        float4 y = *(const float4*)(sp + 4);
        bf16x8 o;
        o[0] = (short)f2bf(x.x); o[1] = (short)f2bf(x.y);
        o[2] = (short)f2bf(x.z); o[3] = (short)f2bf(x.w);
        o[4] = (short)f2bf(y.x); o[5] = (short)f2bf(y.y);
        o[6] = (short)f2bf(y.z); o[7] = (short)f2bf(y.w);
        *(bf16x8*)(dst + (size_t)chunk * 8) = o;
    }
}

// ---------------------------------------------------------------------------
// Fat kernel kAP (r16 = r14 base, Kcn LDS copy ELIMINATED):
// GEMM2's B-operand (row c, 8 contiguous n) loads straight from global K into
// registers, issued in the SAME burst as the staging prefetch for the same
// subtile (same cache lines -> L2-hit; r5's failure was re-reading ACROSS
// barriers). Double-buffered via bf16 convert before the burst overwrites.
// Removes per-thread/subtile: 8 Kcn LDS-writes + 4 b128 GEMM2 LDS-reads
// (~34% of LDS traffic), and LDS 79.9KB -> 38.9KB => 4 blocks/CU.
// kA LDS: Knc[32][520] swz (33280) | A1[64][40] (5120) | sc/sh (512) = 38912
// ---------------------------------------------------------------------------
__global__ __launch_bounds__(512, 1)
void kAP(const float* __restrict__ key, const unsigned short* __restrict__ wfA,
         const float* __restrict__ gmaA, const float* __restrict__ btaA,
         const float* __restrict__ muA, const float* __restrict__ varA,
         float* __restrict__ part, float* __restrict__ ssqp,
         const float* __restrict__ query, const unsigned short* __restrict__ wfP,
         const float* __restrict__ gmaP, const float* __restrict__ btaP,
         const float* __restrict__ muP, const float* __restrict__ varP,
         unsigned short* __restrict__ a2T) {
    extern __shared__ char smem[];
    const int id = blockIdx.x;
    const int nA = NCHUNK * NB;
    const int tid = threadIdx.x;
    const int w = tid >> 6;
    const int lane = tid & 63;
    const int q = lane >> 4;
    const int r = lane & 15;
    const f32x4 fz = {0.f, 0.f, 0.f, 0.f};

    if (id < nA) {
        // ================= kA body =================
        unsigned short* Knc = (unsigned short*)smem;                 // [32][520] swz
        unsigned short* A1  = (unsigned short*)(smem + 33280);       // [64][40]
        float* sc = (float*)(smem + 38400);
        float* sh = sc + NL;

        const int chunk = id % NCHUNK;
        const int b     = id / NCHUNK;
        const int n0    = chunk * (NSUB * NTA);

        if (tid < NL) {
            float s = gmaA[tid] * rsqrtf(varA[tid] + 1e-5f);
            sc[tid] = s;
            sh[tid] = btaA[tid] - muA[tid] * s;
        }

        const int l0  = (w & 3) * 16;
        const int nc0 = (w >> 2) * 16;
        const int c0  = w * 64;
        const int na = nc0 + r;
        const int ga = (na >> 2) & 7;
        const unsigned short* wfp = wfA + ((size_t)((w & 3) * 1024 + q * 16 + r)) * 8;

        const int i4  = tid & 7;
        const int cb0 = tid >> 3;
        const float* kpb = key + (size_t)b * NC * NN + n0;
        // GEMM2-B per-lane global row base: c = c0 + fc*16 + r, cols q*8..+8
        const float* g2base = kpb + (size_t)(c0 + r) * NN + q * 8;

        // prologue: staging prefetch + GEMM2-B regs for subtile 0 (same burst)
        float4 prv[8];
        #pragma unroll
        for (int p = 0; p < 8; p++)
            prv[p] = *(const float4*)(kpb + (size_t)(cb0 + 64 * p) * NN + i4 * 4);
        float4 g2v[8];
        #pragma unroll
        for (int fc = 0; fc < 4; fc++) {
            const float* gp = g2base + (size_t)(fc * 16) * NN;
            g2v[fc * 2]     = *(const float4*)gp;
            g2v[fc * 2 + 1] = *(const float4*)(gp + 4);
        }

        f32x4 acc2[4][4];
        #pragma unroll
        for (int fm = 0; fm < 4; fm++)
            #pragma unroll
            for (int fc = 0; fc < 4; fc++) acc2[fm][fc] = fz;
        float s_acc = 0.f;

        for (int s = 0; s < NSUB; s++) {
            __syncthreads();

            // ---- stage Knc (swizzled transpose, u16) from prv ----
            #pragma unroll
            for (int p = 0; p < 8; p++) {
                int c = cb0 + 64 * p;
                uint2 pk;
                pk.x = (uint32_t)f2bf(prv[p].x) | ((uint32_t)f2bf(prv[p].y) << 16);
                pk.y = (uint32_t)f2bf(prv[p].z) | ((uint32_t)f2bf(prv[p].w) << 16);
                int cs = (((c >> 3) ^ i4) << 3) | (c & 7);
                int j = i4 * 4;
                Knc[(j + 0) * 520 + cs] = (unsigned short)(pk.x);
                Knc[(j + 1) * 520 + cs] = (unsigned short)(pk.x >> 16);
                Knc[(j + 2) * 520 + cs] = (unsigned short)(pk.y);
                Knc[(j + 3) * 520 + cs] = (unsigned short)(pk.y >> 16);
            }

            // ---- convert current GEMM2-B regs to bf16 (before overwrite) ----
            bf16x8 bbf[4];
            #pragma unroll
            for (int fc = 0; fc < 4; fc++) {
                bf16x8 t;
                t[0] = (short)f2bf(g2v[fc * 2].x);     t[1] = (short)f2bf(g2v[fc * 2].y);
                t[2] = (short)f2bf(g2v[fc * 2].z);     t[3] = (short)f2bf(g2v[fc * 2].w);
                t[4] = (short)f2bf(g2v[fc * 2 + 1].x); t[5] = (short)f2bf(g2v[fc * 2 + 1].y);
                t[6] = (short)f2bf(g2v[fc * 2 + 1].z); t[7] = (short)f2bf(g2v[fc * 2 + 1].w);
                bbf[fc] = t;
            }
            __syncthreads();

            // ---- prefetch NEXT sub-tile: staging + GEMM2-B (same burst) ----
            if (s + 1 < NSUB) {
                const float* kp = kpb + (s + 1) * NTA;
                #pragma unroll
                for (int p = 0; p < 8; p++)
                    prv[p] = *(const float4*)(kp + (size_t)(cb0 + 64 * p) * NN + i4 * 4);
                const float* g2n = g2base + (s + 1) * NTA;
                #pragma unroll
                for (int fc = 0; fc < 4; fc++) {
                    const float* gp = g2n + (size_t)(fc * 16) * NN;
                    g2v[fc * 2]     = *(const float4*)gp;
                    g2v[fc * 2 + 1] = *(const float4*)(gp + 4);
                }
            }

            // GEMM1 (swapped): lane holds l=l0+r, n = nc0 + q*4 + i
            {
                f32x4 acc0 = fz;
                #pragma unroll
                for (int it = 0; it < 16; it++) {
                    bf16x8 af = *(const bf16x8*)&wfp[it * 512];
                    bf16x8 b0 = *(const bf16x8*)&Knc[na * 520 + (((it * 4 + q) ^ ga) << 3)];
                    acc0 = __builtin_amdgcn_mfma_f32_16x16x32_bf16(b0, af, acc0, 0, 0, 0);
                }
                const int l = l0 + r;
                const float scl = sc[l], shf = sh[l];
                ushort4 t;
                float v0 = fmaxf(acc0[0] * scl + shf, 0.f);
                float v1 = fmaxf(acc0[1] * scl + shf, 0.f);
                float v2 = fmaxf(acc0[2] * scl + shf, 0.f);
                float v3 = fmaxf(acc0[3] * scl + shf, 0.f);
                t.x = f2bf(v0); t.y = f2bf(v1); t.z = f2bf(v2); t.w = f2bf(v3);
                s_acc += v0 * v0 + v1 * v1 + v2 * v2 + v3 * v3;
                *(ushort4*)&A1[l * 40 + nc0 + q * 4] = t;
            }
            __syncthreads();

            // GEMM2 (swapped): B from registers (global/L2), A from A1 LDS
            {
                bf16x8 a[4];
                #pragma unroll
                for (int fm = 0; fm < 4; fm++)
                    a[fm] = *(const bf16x8*)&A1[(fm * 16 + r) * 40 + q * 8];
                #pragma unroll
                for (int fc = 0; fc < 4; fc++)
                    #pragma unroll
                    for (int fm = 0; fm < 4; fm++)
                        acc2[fm][fc] = __builtin_amdgcn_mfma_f32_16x16x32_bf16(bbf[fc], a[fm], acc2[fm][fc], 0, 0, 0);
            }
        }

        {
            float s = s_acc;
            s += __shfl_xor(s, 16);
            s += __shfl_xor(s, 32);
            float* sp = ssqp + (((size_t)(chunk * NB + b) * 2 + (w >> 2))) * NL;
            if (lane < 16) sp[l0 + lane] = s;
        }

        // part in REGISTER ORDER: each store-inst = 1 KB contiguous.
        float* wp2 = part + ((size_t)(chunk * NB + b) * 8 + w) * 4096 + lane * 4;
        #pragma unroll
        for (int fm = 0; fm < 4; fm++)
            #pragma unroll
            for (int fc = 0; fc < 4; fc++)
                *(f32x4*)(wp2 + (fm * 4 + fc) * 256) = acc2[fm][fc];
    } else {
        // ================= kP body (r14, unchanged) =================
        unsigned short* Qnc = (unsigned short*)smem;               // [32][520] swz
        unsigned short* A2  = (unsigned short*)(smem + 33280);     // [32][72]
        float* ssn = (float*)(smem + 33280 + 4608);                // [32]
        float* sc = ssn + 32;
        float* sh = sc + 64;

        const int pid = id - nA;
        const int b   = pid / NTILES32;
        const int n0  = (pid % NTILES32) * NTA;

        if (tid < 64) {
            float s = gmaP[tid] * rsqrtf(varP[tid] + 1e-5f);
            sc[tid] = s;
            sh[tid] = btaP[tid] - muP[tid] * s;
        }
        if (tid < 32) ssn[tid] = 0.f;

        const int i4  = tid & 7;
        const int cb0 = tid >> 3;
        const float* qp = query + (size_t)b * NC * NN + n0;
        float4 qv[8];
        #pragma unroll
        for (int p = 0; p < 8; p++)
            qv[p] = *(const float4*)(qp + (size_t)(cb0 + 64 * p) * NN + i4 * 4);
        #pragma unroll
        for (int p = 0; p < 8; p++) {
            int c = cb0 + 64 * p;
            int cs = (((c >> 3) ^ i4) << 3) | (c & 7);
            int j = i4 * 4;
            Qnc[(j + 0) * 520 + cs] = f2bf(qv[p].x);
            Qnc[(j + 1) * 520 + cs] = f2bf(qv[p].y);
            Qnc[(j + 2) * 520 + cs] = f2bf(qv[p].z);
            Qnc[(j + 3) * 520 + cs] = f2bf(qv[p].w);
        }
        __syncthreads();

        const int l0 = (w & 3) * 16, nc0 = (w >> 2) * 16;
        const int na = nc0 + r;
        const int ga = (na >> 2) & 7;
        const unsigned short* wfp = wfP + ((size_t)((w & 3) * 1024 + q * 16 + r)) * 8;

        f32x4 acc0 = fz;
        #pragma unroll
        for (int it = 0; it < 16; it++) {
            bf16x8 af = *(const bf16x8*)&wfp[it * 512];
            bf16x8 b0 = *(const bf16x8*)&Qnc[na * 520 + (((it * 4 + q) ^ ga) << 3)];
            acc0 = __builtin_amdgcn_mfma_f32_16x16x32_bf16(af, b0, acc0, 0, 0, 0);
        }

        float s0 = 0.f;
        {
            unsigned short t0[4];
            #pragma unroll
            for (int i = 0; i < 4; i++) {
                int l = l0 + q * 4 + i;
                float v0 = fmaxf(acc0[i] * sc[l] + sh[l], 0.f);
                t0[i] = f2bf(v0);
                s0 += v0 * v0;
            }
            *(ushort4*)&A2[na * 72 + l0 + 4 * q] = make_ushort4(t0[0], t0[1], t0[2], t0[3]);
        }

        s0 += __shfl_xor(s0, 16);
        s0 += __shfl_xor(s0, 32);
        if (lane < 16) atomicAdd(&ssn[na], s0);
        __syncthreads();

        if (tid < 256) {
            int row = tid >> 3, ch = tid & 7;
            float inv = 1.f / fmaxf(sqrtf(ssn[row]), 1e-12f);
            bf16x8 x = *(const bf16x8*)&A2[row * 72 + ch * 8];
            bf16x8 o;
            #pragma unroll
            for (int k = 0; k < 8; k++)
                o[k] = (short)f2bf(bf2f((unsigned short)x[k]) * inv);
            *(bf16x8*)&a2T[((size_t)b * NN + n0 + row) * 64 + ch * 8] = o;
        }
    }
}

// ---------------------------------------------------------------------------
// Kernel R: inverse-map reduce of register-ordered part.
// ---------------------------------------------------------------------------
__global__ __launch_bounds__(256)
void kR(const float* __restrict__ part, float* __restrict__ latu) {
    int gid = blockIdx.x * 256 + threadIdx.x;   // 0..65535
    int lane = gid & 63;
    int fc = (gid >> 6) & 3;
    int fm = (gid >> 8) & 3;
    int w  = (gid >> 10) & 7;
    int b  = gid >> 13;
    int q = lane >> 4, r = lane & 15;

    const float* src = part + ((size_t)(b * 8 + w) * 16 + fm * 4 + fc) * 256 + lane * 4;
    f32x4 acc = {0.f, 0.f, 0.f, 0.f};
    for (int ch = 0; ch < NCHUNK; ch++) {
        f32x4 v = *(const f32x4*)(src + (size_t)ch * (NB * 8 * 4096));
        acc += v;
    }
    float* dst = latu + ((size_t)(b * 64 + fm * 16 + r)) * NC + w * 64 + fc * 16 + q * 4;
    *(f32x4*)dst = acc;
}

// ---------------------------------------------------------------------------
// Kernel B (one block per b): ssq reduce; latent norm; aff softmax; latent2.
// ---------------------------------------------------------------------------
__global__ __launch_bounds__(256, 1)
void kB(const float* __restrict__ latu, const float* __restrict__ ssqp,
        unsigned short* __restrict__ lat2T) {
    extern __shared__ char smem[];
    unsigned short* Lb = (unsigned short*)smem;             // [64][520]
    unsigned short* Lt = (unsigned short*)(smem + 66560);   // [512][72]
    float* aff = (float*)(smem + 140288);                   // [64][68]
    float* inv_nl = (float*)(smem + 157696);
    float* s_c = inv_nl + 64;

    const int tid = threadIdx.x;
    const int b = blockIdx.x;

    if (tid < 64) {
        float s = 0.f;
        for (int ch = 0; ch < NCHUNK; ch++) {
            size_t base = (((size_t)ch * NB + b) * 2) * NL + tid;
            s += ssqp[base] + ssqp[base + NL];
        }
        inv_nl[tid] = 1.f / fmaxf(sqrtf(s), 1e-12f);
    }
    __syncthreads();

    const float* lu = latu + (size_t)b * NL * NC;
    for (int idx = tid; idx < NL * (NC / 4); idx += 256) {
        int l = idx >> 7;
        int c = (idx & 127) << 2;
        float4 v = *(const float4*)(lu + l * NC + c);
        float inv = inv_nl[l];
        unsigned short b0 = f2bf(v.x * inv), b1 = f2bf(v.y * inv);
        unsigned short b2 = f2bf(v.z * inv), b3 = f2bf(v.w * inv);
        uint32_t* d = (uint32_t*)&Lb[l * 520 + c];
        d[0] = (uint32_t)b0 | ((uint32_t)b1 << 16);
        d[1] = (uint32_t)b2 | ((uint32_t)b3 << 16);
        Lt[(c + 0) * 72 + l] = b0;
        Lt[(c + 1) * 72 + l] = b1;
        Lt[(c + 2) * 72 + l] = b2;
        Lt[(c + 3) * 72 + l] = b3;
    }
    __syncthreads();

    {
        int l = tid >> 2, p = tid & 3;
        float s = 0.f;
        for (int c = p * 128; c < p * 128 + 128; c += 4) {
            const unsigned short* d = &Lb[l * 520 + c];
            float v0 = bf2f(d[0]), v1 = bf2f(d[1]), v2 = bf2f(d[2]), v3 = bf2f(d[3]);
            s += v0 * v0 + v1 * v1 + v2 * v2 + v3 * v3;
        }
        s += __shfl_xor(s, 1);
        s += __shfl_xor(s, 2);
        if (p == 0) s_c[l] = 1.f / fmaxf(sqrtf(s), 1e-12f);
    }
    __syncthreads();

    const int w = tid >> 6, lane = tid & 63, q = lane >> 4, r = lane & 15;
    const f32x4 fz = {0.f, 0.f, 0.f, 0.f};

    {
        f32x4 g[4];
        #pragma unroll
        for (int fm = 0; fm < 4; fm++) g[fm] = fz;
        for (int kc = 0; kc < NC; kc += 32) {
            bf16x8 a = *(const bf16x8*)&Lb[(w * 16 + r) * 520 + kc + q * 8];
            #pragma unroll
            for (int fm = 0; fm < 4; fm++) {
                bf16x8 bb = *(const bf16x8*)&Lb[(fm * 16 + r) * 520 + kc + q * 8];
                g[fm] = __builtin_amdgcn_mfma_f32_16x16x32_bf16(a, bb, g[fm], 0, 0, 0);
            }
        }
        #pragma unroll
        for (int fm = 0; fm < 4; fm++)
            #pragma unroll
            for (int i = 0; i < 4; i++) {
                int l = w * 16 + q * 4 + i;
                int m = fm * 16 + r;
                aff[l * 68 + m] = g[fm][i] * s_c[l] * s_c[m];
            }
    }
    __syncthreads();

    {
        int l = tid >> 2, p = tid & 3;
        float e[16];
        float mx = -1e30f;
        #pragma unroll
        for (int k = 0; k < 16; k++) mx = fmaxf(mx, aff[l * 68 + p * 16 + k]);
        mx = fmaxf(mx, __shfl_xor(mx, 1));
        mx = fmaxf(mx, __shfl_xor(mx, 2));
        float s = 0.f;
        #pragma unroll
        for (int k = 0; k < 16; k++) { e[k] = __expf(aff[l * 68 + p * 16 + k] - mx); s += e[k]; }
        s += __shfl_xor(s, 1);
        s += __shfl_xor(s, 2);
        float invs = 1.f / s;
        __syncthreads();
        #pragma unroll
        for (int k = 0; k < 16; k++) aff[l * 68 + p * 16 + k] = e[k] * invs;
    }
    __syncthreads();

    {
        f32x4 acc[4][8];
        #pragma unroll
        for (int fm = 0; fm < 4; fm++)
            #pragma unroll
            for (int fc = 0; fc < 8; fc++) acc[fm][fc] = fz;
        #pragma unroll
        for (int km = 0; km < 64; km += 32) {
            bf16x8 a[4];
            #pragma unroll
            for (int fm = 0; fm < 4; fm++) {
                const float* ap = &aff[(fm * 16 + r) * 68 + km + q * 8];
                float4 x = *(const float4*)ap;
                float4 y = *(const float4*)(ap + 4);
                bf16x8 t;
                t[0] = (short)f2bf(x.x); t[1] = (short)f2bf(x.y);
                t[2] = (short)f2bf(x.z); t[3] = (short)f2bf(x.w);
                t[4] = (short)f2bf(y.x); t[5] = (short)f2bf(y.y);
                t[6] = (short)f2bf(y.z); t[7] = (short)f2bf(y.w);
                a[fm] = t;
            }
            #pragma unroll
            for (int fc = 0; fc < 8; fc++) {
                bf16x8 bb = *(const bf16x8*)&Lt[(w * 128 + fc * 16 + r) * 72 + km + q * 8];
                #pragma unroll
                for (int fm = 0; fm < 4; fm++)
                    acc[fm][fc] = __builtin_amdgcn_mfma_f32_16x16x32_bf16(a[fm], bb, acc[fm][fc], 0, 0, 0);
            }
        }
        unsigned short* out = lat2T + (size_t)b * NC * NL;
        #pragma unroll
        for (int fm = 0; fm < 4; fm++)
            #pragma unroll
            for (int fc = 0; fc < 8; fc++)
                #pragma unroll
                for (int i = 0; i < 4; i++) {
                    int l = fm * 16 + q * 4 + i;
                    int c = w * 128 + fc * 16 + r;
                    out[c * 64 + l] = f2bf(acc[fm][fc][i]);
                }
    }
}

// ---------------------------------------------------------------------------
// Kernel C3: operand-swapped + LDS bounce (4-row x 256 B contiguous stores)
// ---------------------------------------------------------------------------
__global__ __launch_bounds__(256, 4)
void kC3(const unsigned short* __restrict__ a2T,
         const unsigned short* __restrict__ lat2T, float* __restrict__ out) {
    __shared__ unsigned short At[64 * 72];   // [n][72 l]
    __shared__ float Bnc[4][16][68];         // per-wave [c16][n64+4]

    const int tid = threadIdx.x;
    const int b = blockIdx.y;
    const int n0 = blockIdx.x * NT;

    const unsigned short* src = a2T + ((size_t)b * NN + n0) * 64;
    #pragma unroll
    for (int k = 0; k < 2; k++) {
        int idx = tid + k * 256;
        int row = idx >> 3, ch = idx & 7;
        *(uint4*)&At[row * 72 + ch * 8] = *(const uint4*)&src[row * 64 + ch * 8];
    }
    __syncthreads();

    const int w = tid >> 6, lane = tid & 63, q = lane >> 4, r = lane & 15;
    const f32x4 fz = {0.f, 0.f, 0.f, 0.f};
    const unsigned short* Ab = lat2T + (size_t)b * NC * NL;
    float* op = out + (size_t)b * NC * NN + n0;

    #pragma unroll
    for (int half = 0; half < 2; half++) {
        int cb = w * 128 + half * 64;
        f32x4 acc[4][4];
        #pragma unroll
        for (int fm = 0; fm < 4; fm++)
            #pragma unroll
            for (int fn = 0; fn < 4; fn++) acc[fm][fn] = fz;
        #pragma unroll
        for (int kl = 0; kl < 64; kl += 32) {
            bf16x8 a[4];
            #pragma unroll
            for (int fm = 0; fm < 4; fm++)
                a[fm] = *(const bf16x8*)&Ab[(size_t)(cb + fm * 16 + r) * 64 + kl + q * 8];
            #pragma unroll
            for (int fn = 0; fn < 4; fn++) {
                bf16x8 bb = *(const bf16x8*)&At[(fn * 16 + r) * 72 + kl + q * 8];
                #pragma unroll
                for (int fm = 0; fm < 4; fm++)
                    acc[fm][fn] = __builtin_amdgcn_mfma_f32_16x16x32_bf16(bb, a[fm], acc[fm][fn], 0, 0, 0);
            }
        }
        #pragma unroll
        for (int fm = 0; fm < 4; fm++) {
            #pragma unroll
            for (int fn = 0; fn < 4; fn++)
                *(f32x4*)&Bnc[w][r][fn * 16 + q * 4] = acc[fm][fn];
            #pragma unroll
            for (int rb = 0; rb < 4; rb++) {
                int crow = rb * 4 + (lane >> 4);
                f32x4 v = *(const f32x4*)&Bnc[w][crow][(lane & 15) * 4];
                *(f32x4*)(op + (size_t)(cb + fm * 16 + crow) * NN + (lane & 15) * 4) = v;
            }
        }
    }
}

// ---------------------------------------------------------------------------
extern "C" void kernel_launch(void* const* d_in, const int* in_sizes, int n_in,
                              void* d_out, int out_size, void* d_ws, size_t ws_size,
                              hipStream_t stream) {
    (void)in_sizes; (void)n_in; (void)out_size; (void)ws_size;
    const float* query = (const float*)d_in[0];
    const float* key   = (const float*)d_in[1];
    const float* phi_w = (const float*)d_in[2];
    const float* phi_g = (const float*)d_in[3];
    const float* phi_b = (const float*)d_in[4];
    const float* phi_m = (const float*)d_in[5];
    const float* phi_v = (const float*)d_in[6];
    const float* php_w = (const float*)d_in[7];
    const float* php_g = (const float*)d_in[8];
    const float* php_b = (const float*)d_in[9];
    const float* php_m = (const float*)d_in[10];
    const float* php_v = (const float*)d_in[11];
    float* out = (float*)d_out;

    char* ws = (char*)d_ws;
    size_t off = 0;
    float* part = (float*)(ws + off);           off += (size_t)NCHUNK * NB * NL * NC * 4;  // 14.68 MB
    float* ssqp = (float*)(ws + off);           off += (size_t)NCHUNK * NB * 2 * NL * 4;
    float* latu = (float*)(ws + off);           off += 1048576;
    unsigned short* lat2T = (unsigned short*)(ws + off); off += 524288;
    unsigned short* a2T   = (unsigned short*)(ws + off); off += 6422528;
    unsigned short* wfA   = (unsigned short*)(ws + off); off += 65536;
    unsigned short* wfP   = (unsigned short*)(ws + off); off += 65536;

    (void)hipFuncSetAttribute((const void*)kAP, hipFuncAttributeMaxDynamicSharedMemorySize, 38912);
    (void)hipFuncSetAttribute((const void*)kB, hipFuncAttributeMaxDynamicSharedMemorySize, 158208);

    kW<<<dim3(2), 512, 0, stream>>>(phi_w, php_w, wfA, wfP);
    int nblocks = NCHUNK * NB + NTILES32 * NB;
    kAP<<<dim3(nblocks), 512, 38912, stream>>>(key, wfA, phi_g, phi_b, phi_m, phi_v,
                                               part, ssqp,
                                               query, wfP, php_g, php_b, php_m, php_v, a2T);
    kR<<<dim3(256), 256, 0, stream>>>(part, latu);
    kB<<<dim3(NB), 256, 158208, stream>>>(latu, ssqp, lat2T);
    kC3<<<dim3(NTILES, NB), 256, 0, stream>>>(a2T, lat2T, out);
}

// Round 17
// 117.805 us; speedup vs baseline: 1.5150x; 1.5150x over previous
//
#include <hip/hip_runtime.h>
#include <stdint.h>
#include <stddef.h>

#define NB 8
#define NC 512
#define NL 64
#define NN 6272
#define NT 64
#define NTILES (NN / NT)    // 98
#define NTA 32              // kA/kP sub-tile width (n)
#define NTILES32 (NN / NTA) // 196
#define NCHUNK 28
#define NSUB (NTILES32 / NCHUNK)  // 7

typedef short bf16x8 __attribute__((ext_vector_type(8)));
typedef float f32x4 __attribute__((ext_vector_type(4)));

__device__ __forceinline__ unsigned short f2bf(float f) {
    uint32_t u = __float_as_uint(f);
    u += 0x7fffu + ((u >> 16) & 1u);
    return (unsigned short)(u >> 16);
}
__device__ __forceinline__ float bf2f(unsigned short s) {
    return __uint_as_float(((uint32_t)s) << 16);
}

// ---------------------------------------------------------------------------
// Kernel W: repack 64x512 f32 weights into fragment-ordered bf16.
// ---------------------------------------------------------------------------
__global__ __launch_bounds__(512)
void kW(const float* __restrict__ w0, const float* __restrict__ w1,
        unsigned short* __restrict__ f0, unsigned short* __restrict__ f1) {
    const float* src = blockIdx.x ? w1 : w0;
    unsigned short* dst = blockIdx.x ? f1 : f0;
    int t = threadIdx.x;
    #pragma unroll
    for (int j = 0; j < 8; j++) {
        int chunk = t + j * 512;
        int r = chunk & 15, q = (chunk >> 4) & 3, it = (chunk >> 6) & 15, lg = chunk >> 10;
        const float* sp = src + (size_t)(lg * 16 + r) * NC + it * 32 + q * 8;
        float4 x = *(const float4*)sp;
        float4 y = *(const float4*)(sp + 4);
        bf16x8 o;
        o[0] = (short)f2bf(x.x); o[1] = (short)f2bf(x.y);
        o[2] = (short)f2bf(x.z); o[3] = (short)f2bf(x.w);
        o[4] = (short)f2bf(y.x); o[5] = (short)f2bf(y.y);
        o[6] = (short)f2bf(y.z); o[7] = (short)f2bf(y.w);
        *(bf16x8*)(dst + (size_t)chunk * 8) = o;
    }
}

// ---------------------------------------------------------------------------
// Fat kernel kAP (r17 = r14 with NCHUNK 14 -> 28): halves the serial kA pole
// (nsub 14 -> 7) for load balance; part traffic 14.7 -> 29.4 MB each way
// (register-order contiguous). r16's Kcn-from-global experiment REVERTED
// (FETCH +14MB, kAP +59us). Two-layout LDS staging restored.
// ---------------------------------------------------------------------------
__global__ __launch_bounds__(512, 1)
void kAP(const float* __restrict__ key, const unsigned short* __restrict__ wfA,
         const float* __restrict__ gmaA, const float* __restrict__ btaA,
         const float* __restrict__ muA, const float* __restrict__ varA,
         float* __restrict__ part, float* __restrict__ ssqp,
         const float* __restrict__ query, const unsigned short* __restrict__ wfP,
         const float* __restrict__ gmaP, const float* __restrict__ btaP,
         const float* __restrict__ muP, const float* __restrict__ varP,
         unsigned short* __restrict__ a2T) {
    extern __shared__ char smem[];
    const int id = blockIdx.x;
    const int nA = NCHUNK * NB;
    const int tid = threadIdx.x;
    const int w = tid >> 6;
    const int lane = tid & 63;
    const int q = lane >> 4;
    const int r = lane & 15;
    const f32x4 fz = {0.f, 0.f, 0.f, 0.f};

    if (id < nA) {
        // ================= kA body =================
        unsigned short* Knc = (unsigned short*)smem;                 // [32][520] swz
        unsigned short* Kcn = (unsigned short*)(smem + 33280);       // [512][40]
        unsigned short* A1  = (unsigned short*)(smem + 74240);       // [64][40]
        float* sc = (float*)(smem + 79360);
        float* sh = sc + NL;

        const int chunk = id % NCHUNK;
        const int b     = id / NCHUNK;
        const int n0    = chunk * (NSUB * NTA);

        if (tid < NL) {
            float s = gmaA[tid] * rsqrtf(varA[tid] + 1e-5f);
            sc[tid] = s;
            sh[tid] = btaA[tid] - muA[tid] * s;
        }

        const int l0  = (w & 3) * 16;
        const int nc0 = (w >> 2) * 16;
        const int c0  = w * 64;
        const int na = nc0 + r;
        const int ga = (na >> 2) & 7;
        const unsigned short* wfp = wfA + ((size_t)((w & 3) * 1024 + q * 16 + r)) * 8;

        const int i4  = tid & 7;
        const int cb0 = tid >> 3;
        const float* kpb = key + (size_t)b * NC * NN + n0;

        // prefetch: RAW float4 (no conversion between loads)
        float4 prv[8];
        #pragma unroll
        for (int p = 0; p < 8; p++)
            prv[p] = *(const float4*)(kpb + (size_t)(cb0 + 64 * p) * NN + i4 * 4);

        f32x4 acc2[4][4];
        #pragma unroll
        for (int fm = 0; fm < 4; fm++)
            #pragma unroll
            for (int fc = 0; fc < 4; fc++) acc2[fm][fc] = fz;
        float s_acc = 0.f;

        for (int s = 0; s < NSUB; s++) {
            __syncthreads();

            // ---- convert + write prefetched sub-tile into both layouts ----
            #pragma unroll
            for (int p = 0; p < 8; p++) {
                int c = cb0 + 64 * p;
                uint2 pk;
                pk.x = (uint32_t)f2bf(prv[p].x) | ((uint32_t)f2bf(prv[p].y) << 16);
                pk.y = (uint32_t)f2bf(prv[p].z) | ((uint32_t)f2bf(prv[p].w) << 16);
                *(uint2*)&Kcn[c * 40 + i4 * 4] = pk;
                int cs = (((c >> 3) ^ i4) << 3) | (c & 7);
                int j = i4 * 4;
                Knc[(j + 0) * 520 + cs] = (unsigned short)(pk.x);
                Knc[(j + 1) * 520 + cs] = (unsigned short)(pk.x >> 16);
                Knc[(j + 2) * 520 + cs] = (unsigned short)(pk.y);
                Knc[(j + 3) * 520 + cs] = (unsigned short)(pk.y >> 16);
            }
            __syncthreads();

            // ---- prefetch NEXT sub-tile (pure loads, stay outstanding) ----
            if (s + 1 < NSUB) {
                const float* kp = kpb + (s + 1) * NTA;
                #pragma unroll
                for (int p = 0; p < 8; p++)
                    prv[p] = *(const float4*)(kp + (size_t)(cb0 + 64 * p) * NN + i4 * 4);
            }

            // GEMM1 (swapped): lane holds l=l0+r, n = nc0 + q*4 + i
            {
                f32x4 acc0 = fz;
                #pragma unroll
                for (int it = 0; it < 16; it++) {
                    bf16x8 af = *(const bf16x8*)&wfp[it * 512];
                    bf16x8 b0 = *(const bf16x8*)&Knc[na * 520 + (((it * 4 + q) ^ ga) << 3)];
                    acc0 = __builtin_amdgcn_mfma_f32_16x16x32_bf16(b0, af, acc0, 0, 0, 0);
                }
                const int l = l0 + r;
                const float scl = sc[l], shf = sh[l];
                ushort4 t;
                float v0 = fmaxf(acc0[0] * scl + shf, 0.f);
                float v1 = fmaxf(acc0[1] * scl + shf, 0.f);
                float v2 = fmaxf(acc0[2] * scl + shf, 0.f);
                float v3 = fmaxf(acc0[3] * scl + shf, 0.f);
                t.x = f2bf(v0); t.y = f2bf(v1); t.z = f2bf(v2); t.w = f2bf(v3);
                s_acc += v0 * v0 + v1 * v1 + v2 * v2 + v3 * v3;
                *(ushort4*)&A1[l * 40 + nc0 + q * 4] = t;
            }
            __syncthreads();

            // GEMM2 (swapped): lane holds c = c0+fc*16+q*4+i (4 contiguous)
            {
                bf16x8 a[4];
                #pragma unroll
                for (int fm = 0; fm < 4; fm++)
                    a[fm] = *(const bf16x8*)&A1[(fm * 16 + r) * 40 + q * 8];
                #pragma unroll
                for (int fc = 0; fc < 4; fc++) {
                    bf16x8 bb = *(const bf16x8*)&Kcn[(c0 + fc * 16 + r) * 40 + q * 8];
                    #pragma unroll
                    for (int fm = 0; fm < 4; fm++)
                        acc2[fm][fc] = __builtin_amdgcn_mfma_f32_16x16x32_bf16(bb, a[fm], acc2[fm][fc], 0, 0, 0);
                }
            }
        }

        {
            float s = s_acc;
            s += __shfl_xor(s, 16);
            s += __shfl_xor(s, 32);
            float* sp = ssqp + (((size_t)(chunk * NB + b) * 2 + (w >> 2))) * NL;
            if (lane < 16) sp[l0 + lane] = s;
        }

        // part in REGISTER ORDER: each store-inst = 1 KB contiguous.
        float* wp2 = part + ((size_t)(chunk * NB + b) * 8 + w) * 4096 + lane * 4;
        #pragma unroll
        for (int fm = 0; fm < 4; fm++)
            #pragma unroll
            for (int fc = 0; fc < 4; fc++)
                *(f32x4*)(wp2 + (fm * 4 + fc) * 256) = acc2[fm][fc];
    } else {
        // ================= kP body =================
        unsigned short* Qnc = (unsigned short*)smem;               // [32][520] swz
        unsigned short* A2  = (unsigned short*)(smem + 33280);     // [32][72]
        float* ssn = (float*)(smem + 33280 + 4608);                // [32]
        float* sc = ssn + 32;
        float* sh = sc + 64;

        const int pid = id - nA;
        const int b   = pid / NTILES32;
        const int n0  = (pid % NTILES32) * NTA;

        if (tid < 64) {
            float s = gmaP[tid] * rsqrtf(varP[tid] + 1e-5f);
            sc[tid] = s;
            sh[tid] = btaP[tid] - muP[tid] * s;
        }
        if (tid < 32) ssn[tid] = 0.f;

        const int i4  = tid & 7;
        const int cb0 = tid >> 3;
        const float* qp = query + (size_t)b * NC * NN + n0;
        float4 qv[8];
        #pragma unroll
        for (int p = 0; p < 8; p++)
            qv[p] = *(const float4*)(qp + (size_t)(cb0 + 64 * p) * NN + i4 * 4);
        #pragma unroll
        for (int p = 0; p < 8; p++) {
            int c = cb0 + 64 * p;
            int cs = (((c >> 3) ^ i4) << 3) | (c & 7);
            int j = i4 * 4;
            Qnc[(j + 0) * 520 + cs] = f2bf(qv[p].x);
            Qnc[(j + 1) * 520 + cs] = f2bf(qv[p].y);
            Qnc[(j + 2) * 520 + cs] = f2bf(qv[p].z);
            Qnc[(j + 3) * 520 + cs] = f2bf(qv[p].w);
        }
        __syncthreads();

        const int l0 = (w & 3) * 16, nc0 = (w >> 2) * 16;
        const int na = nc0 + r;
        const int ga = (na >> 2) & 7;
        const unsigned short* wfp = wfP + ((size_t)((w & 3) * 1024 + q * 16 + r)) * 8;

        f32x4 acc0 = fz;
        #pragma unroll
        for (int it = 0; it < 16; it++) {
            bf16x8 af = *(const bf16x8*)&wfp[it * 512];
            bf16x8 b0 = *(const bf16x8*)&Qnc[na * 520 + (((it * 4 + q) ^ ga) << 3)];
            acc0 = __builtin_amdgcn_mfma_f32_16x16x32_bf16(af, b0, acc0, 0, 0, 0);
        }

        float s0 = 0.f;
        {
            unsigned short t0[4];
            #pragma unroll
            for (int i = 0; i < 4; i++) {
                int l = l0 + q * 4 + i;
                float v0 = fmaxf(acc0[i] * sc[l] + sh[l], 0.f);
                t0[i] = f2bf(v0);
                s0 += v0 * v0;
            }
            *(ushort4*)&A2[na * 72 + l0 + 4 * q] = make_ushort4(t0[0], t0[1], t0[2], t0[3]);
        }

        s0 += __shfl_xor(s0, 16);
        s0 += __shfl_xor(s0, 32);
        if (lane < 16) atomicAdd(&ssn[na], s0);
        __syncthreads();

        if (tid < 256) {
            int row = tid >> 3, ch = tid & 7;
            float inv = 1.f / fmaxf(sqrtf(ssn[row]), 1e-12f);
            bf16x8 x = *(const bf16x8*)&A2[row * 72 + ch * 8];
            bf16x8 o;
            #pragma unroll
            for (int k = 0; k < 8; k++)
                o[k] = (short)f2bf(bf2f((unsigned short)x[k]) * inv);
            *(bf16x8*)&a2T[((size_t)b * NN + n0 + row) * 64 + ch * 8] = o;
        }
    }
}

// ---------------------------------------------------------------------------
// Kernel R: inverse-map reduce of register-ordered part.
// ---------------------------------------------------------------------------
__global__ __launch_bounds__(256)
void kR(const float* __restrict__ part, float* __restrict__ latu) {
    int gid = blockIdx.x * 256 + threadIdx.x;   // 0..65535
    int lane = gid & 63;
    int fc = (gid >> 6) & 3;
    int fm = (gid >> 8) & 3;
    int w  = (gid >> 10) & 7;
    int b  = gid >> 13;
    int q = lane >> 4, r = lane & 15;

    const float* src = part + ((size_t)(b * 8 + w) * 16 + fm * 4 + fc) * 256 + lane * 4;
    f32x4 acc = {0.f, 0.f, 0.f, 0.f};
    #pragma unroll 4
    for (int ch = 0; ch < NCHUNK; ch++) {
        f32x4 v = *(const f32x4*)(src + (size_t)ch * (NB * 8 * 4096));
        acc += v;
    }
    float* dst = latu + ((size_t)(b * 64 + fm * 16 + r)) * NC + w * 64 + fc * 16 + q * 4;
    *(f32x4*)dst = acc;
}

// ---------------------------------------------------------------------------
// Kernel B (one block per b): ssq reduce; latent norm; aff softmax; latent2.
// ---------------------------------------------------------------------------
__global__ __launch_bounds__(256, 1)
void kB(const float* __restrict__ latu, const float* __restrict__ ssqp,
        unsigned short* __restrict__ lat2T) {
    extern __shared__ char smem[];
    unsigned short* Lb = (unsigned short*)smem;             // [64][520]
    unsigned short* Lt = (unsigned short*)(smem + 66560);   // [512][72]
    float* aff = (float*)(smem + 140288);                   // [64][68]
    float* inv_nl = (float*)(smem + 157696);
    float* s_c = inv_nl + 64;

    const int tid = threadIdx.x;
    const int b = blockIdx.x;

    if (tid < 64) {
        float s = 0.f;
        for (int ch = 0; ch < NCHUNK; ch++) {
            size_t base = (((size_t)ch * NB + b) * 2) * NL + tid;
            s += ssqp[base] + ssqp[base + NL];
        }
        inv_nl[tid] = 1.f / fmaxf(sqrtf(s), 1e-12f);
    }
    __syncthreads();

    const float* lu = latu + (size_t)b * NL * NC;
    for (int idx = tid; idx < NL * (NC / 4); idx += 256) {
        int l = idx >> 7;
        int c = (idx & 127) << 2;
        float4 v = *(const float4*)(lu + l * NC + c);
        float inv = inv_nl[l];
        unsigned short b0 = f2bf(v.x * inv), b1 = f2bf(v.y * inv);
        unsigned short b2 = f2bf(v.z * inv), b3 = f2bf(v.w * inv);
        uint32_t* d = (uint32_t*)&Lb[l * 520 + c];
        d[0] = (uint32_t)b0 | ((uint32_t)b1 << 16);
        d[1] = (uint32_t)b2 | ((uint32_t)b3 << 16);
        Lt[(c + 0) * 72 + l] = b0;
        Lt[(c + 1) * 72 + l] = b1;
        Lt[(c + 2) * 72 + l] = b2;
        Lt[(c + 3) * 72 + l] = b3;
    }
    __syncthreads();

    {
        int l = tid >> 2, p = tid & 3;
        float s = 0.f;
        for (int c = p * 128; c < p * 128 + 128; c += 4) {
            const unsigned short* d = &Lb[l * 520 + c];
            float v0 = bf2f(d[0]), v1 = bf2f(d[1]), v2 = bf2f(d[2]), v3 = bf2f(d[3]);
            s += v0 * v0 + v1 * v1 + v2 * v2 + v3 * v3;
        }
        s += __shfl_xor(s, 1);
        s += __shfl_xor(s, 2);
        if (p == 0) s_c[l] = 1.f / fmaxf(sqrtf(s), 1e-12f);
    }
    __syncthreads();

    const int w = tid >> 6, lane = tid & 63, q = lane >> 4, r = lane & 15;
    const f32x4 fz = {0.f, 0.f, 0.f, 0.f};

    {
        f32x4 g[4];
        #pragma unroll
        for (int fm = 0; fm < 4; fm++) g[fm] = fz;
        for (int kc = 0; kc < NC; kc += 32) {
            bf16x8 a = *(const bf16x8*)&Lb[(w * 16 + r) * 520 + kc + q * 8];
            #pragma unroll
            for (int fm = 0; fm < 4; fm++) {
                bf16x8 bb = *(const bf16x8*)&Lb[(fm * 16 + r) * 520 + kc + q * 8];
                g[fm] = __builtin_amdgcn_mfma_f32_16x16x32_bf16(a, bb, g[fm], 0, 0, 0);
            }
        }
        #pragma unroll
        for (int fm = 0; fm < 4; fm++)
            #pragma unroll
            for (int i = 0; i < 4; i++) {
                int l = w * 16 + q * 4 + i;
                int m = fm * 16 + r;
                aff[l * 68 + m] = g[fm][i] * s_c[l] * s_c[m];
            }
    }
    __syncthreads();

    {
        int l = tid >> 2, p = tid & 3;
        float e[16];
        float mx = -1e30f;
        #pragma unroll
        for (int k = 0; k < 16; k++) mx = fmaxf(mx, aff[l * 68 + p * 16 + k]);
        mx = fmaxf(mx, __shfl_xor(mx, 1));
        mx = fmaxf(mx, __shfl_xor(mx, 2));
        float s = 0.f;
        #pragma unroll
        for (int k = 0; k < 16; k++) { e[k] = __expf(aff[l * 68 + p * 16 + k] - mx); s += e[k]; }
        s += __shfl_xor(s, 1);
        s += __shfl_xor(s, 2);
        float invs = 1.f / s;
        __syncthreads();
        #pragma unroll
        for (int k = 0; k < 16; k++) aff[l * 68 + p * 16 + k] = e[k] * invs;
    }
    __syncthreads();

    {
        f32x4 acc[4][8];
        #pragma unroll
        for (int fm = 0; fm < 4; fm++)
            #pragma unroll
            for (int fc = 0; fc < 8; fc++) acc[fm][fc] = fz;
        #pragma unroll
        for (int km = 0; km < 64; km += 32) {
            bf16x8 a[4];
            #pragma unroll
            for (int fm = 0; fm < 4; fm++) {
                const float* ap = &aff[(fm * 16 + r) * 68 + km + q * 8];
                float4 x = *(const float4*)ap;
                float4 y = *(const float4*)(ap + 4);
                bf16x8 t;
                t[0] = (short)f2bf(x.x); t[1] = (short)f2bf(x.y);
                t[2] = (short)f2bf(x.z); t[3] = (short)f2bf(x.w);
                t[4] = (short)f2bf(y.x); t[5] = (short)f2bf(y.y);
                t[6] = (short)f2bf(y.z); t[7] = (short)f2bf(y.w);
                a[fm] = t;
            }
            #pragma unroll
            for (int fc = 0; fc < 8; fc++) {
                bf16x8 bb = *(const bf16x8*)&Lt[(w * 128 + fc * 16 + r) * 72 + km + q * 8];
                #pragma unroll
                for (int fm = 0; fm < 4; fm++)
                    acc[fm][fc] = __builtin_amdgcn_mfma_f32_16x16x32_bf16(a[fm], bb, acc[fm][fc], 0, 0, 0);
            }
        }
        unsigned short* out = lat2T + (size_t)b * NC * NL;
        #pragma unroll
        for (int fm = 0; fm < 4; fm++)
            #pragma unroll
            for (int fc = 0; fc < 8; fc++)
                #pragma unroll
                for (int i = 0; i < 4; i++) {
                    int l = fm * 16 + q * 4 + i;
                    int c = w * 128 + fc * 16 + r;
                    out[c * 64 + l] = f2bf(acc[fm][fc][i]);
                }
    }
}

// ---------------------------------------------------------------------------
// Kernel C3: operand-swapped + LDS bounce (4-row x 256 B contiguous stores)
// ---------------------------------------------------------------------------
__global__ __launch_bounds__(256, 4)
void kC3(const unsigned short* __restrict__ a2T,
         const unsigned short* __restrict__ lat2T, float* __restrict__ out) {
    __shared__ unsigned short At[64 * 72];   // [n][72 l]
    __shared__ float Bnc[4][16][68];         // per-wave [c16][n64+4]

    const int tid = threadIdx.x;
    const int b = blockIdx.y;
    const int n0 = blockIdx.x * NT;

    const unsigned short* src = a2T + ((size_t)b * NN + n0) * 64;
    #pragma unroll
    for (int k = 0; k < 2; k++) {
        int idx = tid + k * 256;
        int row = idx >> 3, ch = idx & 7;
        *(uint4*)&At[row * 72 + ch * 8] = *(const uint4*)&src[row * 64 + ch * 8];
    }
    __syncthreads();

    const int w = tid >> 6, lane = tid & 63, q = lane >> 4, r = lane & 15;
    const f32x4 fz = {0.f, 0.f, 0.f, 0.f};
    const unsigned short* Ab = lat2T + (size_t)b * NC * NL;
    float* op = out + (size_t)b * NC * NN + n0;

    #pragma unroll
    for (int half = 0; half < 2; half++) {
        int cb = w * 128 + half * 64;
        f32x4 acc[4][4];
        #pragma unroll
        for (int fm = 0; fm < 4; fm++)
            #pragma unroll
            for (int fn = 0; fn < 4; fn++) acc[fm][fn] = fz;
        #pragma unroll
        for (int kl = 0; kl < 64; kl += 32) {
            bf16x8 a[4];
            #pragma unroll
            for (int fm = 0; fm < 4; fm++)
                a[fm] = *(const bf16x8*)&Ab[(size_t)(cb + fm * 16 + r) * 64 + kl + q * 8];
            #pragma unroll
            for (int fn = 0; fn < 4; fn++) {
                bf16x8 bb = *(const bf16x8*)&At[(fn * 16 + r) * 72 + kl + q * 8];
                #pragma unroll
                for (int fm = 0; fm < 4; fm++)
                    acc[fm][fn] = __builtin_amdgcn_mfma_f32_16x16x32_bf16(bb, a[fm], acc[fm][fn], 0, 0, 0);
            }
        }
        #pragma unroll
        for (int fm = 0; fm < 4; fm++) {
            #pragma unroll
            for (int fn = 0; fn < 4; fn++)
                *(f32x4*)&Bnc[w][r][fn * 16 + q * 4] = acc[fm][fn];
            #pragma unroll
            for (int rb = 0; rb < 4; rb++) {
                int crow = rb * 4 + (lane >> 4);
                f32x4 v = *(const f32x4*)&Bnc[w][crow][(lane & 15) * 4];
                *(f32x4*)(op + (size_t)(cb + fm * 16 + crow) * NN + (lane & 15) * 4) = v;
            }
        }
    }
}

// ---------------------------------------------------------------------------
extern "C" void kernel_launch(void* const* d_in, const int* in_sizes, int n_in,
                              void* d_out, int out_size, void* d_ws, size_t ws_size,
                              hipStream_t stream) {
    (void)in_sizes; (void)n_in; (void)out_size; (void)ws_size;
    const float* query = (const float*)d_in[0];
    const float* key   = (const float*)d_in[1];
    const float* phi_w = (const float*)d_in[2];
    const float* phi_g = (const float*)d_in[3];
    const float* phi_b = (const float*)d_in[4];
    const float* phi_m = (const float*)d_in[5];
    const float* phi_v = (const float*)d_in[6];
    const float* php_w = (const float*)d_in[7];
    const float* php_g = (const float*)d_in[8];
    const float* php_b = (const float*)d_in[9];
    const float* php_m = (const float*)d_in[10];
    const float* php_v = (const float*)d_in[11];
    float* out = (float*)d_out;

    char* ws = (char*)d_ws;
    size_t off = 0;
    float* part = (float*)(ws + off);           off += (size_t)NCHUNK * NB * NL * NC * 4;  // 29.36 MB
    float* ssqp = (float*)(ws + off);           off += (size_t)NCHUNK * NB * 2 * NL * 4;
    float* latu = (float*)(ws + off);           off += 1048576;
    unsigned short* lat2T = (unsigned short*)(ws + off); off += 524288;
    unsigned short* a2T   = (unsigned short*)(ws + off); off += 6422528;
    unsigned short* wfA   = (unsigned short*)(ws + off); off += 65536;
    unsigned short* wfP   = (unsigned short*)(ws + off); off += 65536;

    (void)hipFuncSetAttribute((const void*)kAP, hipFuncAttributeMaxDynamicSharedMemorySize, 79872);
    (void)hipFuncSetAttribute((const void*)kB, hipFuncAttributeMaxDynamicSharedMemorySize, 158208);

    kW<<<dim3(2), 512, 0, stream>>>(phi_w, php_w, wfA, wfP);
    int nblocks = NCHUNK * NB + NTILES32 * NB;
    kAP<<<dim3(nblocks), 512, 79872, stream>>>(key, wfA, phi_g, phi_b, phi_m, phi_v,
                                               part, ssqp,
                                               query, wfP, php_g, php_b, php_m, php_v, a2T);
    kR<<<dim3(256), 256, 0, stream>>>(part, latu);
    kB<<<dim3(NB), 256, 158208, stream>>>(latu, ssqp, lat2T);
    kC3<<<dim3(NTILES, NB), 256, 0, stream>>>(a2T, lat2T, out);
}

// Round 18
// 115.505 us; speedup vs baseline: 1.5451x; 1.0199x over previous
//
#include <hip/hip_runtime.h>
#include <stdint.h>
#include <stddef.h>

#define NB 8
#define NC 512
#define NL 64
#define NN 6272
#define NT 64
#define NTILES (NN / NT)    // 98
#define NTA 32              // kA/kP sub-tile width (n)
#define NTILES32 (NN / NTA) // 196
#define NCHUNK 14
#define NSUB (NTILES32 / NCHUNK)  // 14

typedef short bf16x8 __attribute__((ext_vector_type(8)));
typedef float f32x4 __attribute__((ext_vector_type(4)));

__device__ __forceinline__ unsigned short f2bf(float f) {
    uint32_t u = __float_as_uint(f);
    u += 0x7fffu + ((u >> 16) & 1u);
    return (unsigned short)(u >> 16);
}
__device__ __forceinline__ float bf2f(unsigned short s) {
    return __uint_as_float(((uint32_t)s) << 16);
}

// ---------------------------------------------------------------------------
// Kernel W: repack 64x512 f32 weights into fragment-ordered bf16.
// ---------------------------------------------------------------------------
__global__ __launch_bounds__(512)
void kW(const float* __restrict__ w0, const float* __restrict__ w1,
        unsigned short* __restrict__ f0, unsigned short* __restrict__ f1) {
    const float* src = blockIdx.x ? w1 : w0;
    unsigned short* dst = blockIdx.x ? f1 : f0;
    int t = threadIdx.x;
    #pragma unroll
    for (int j = 0; j < 8; j++) {
        int chunk = t + j * 512;
        int r = chunk & 15, q = (chunk >> 4) & 3, it = (chunk >> 6) & 15, lg = chunk >> 10;
        const float* sp = src + (size_t)(lg * 16 + r) * NC + it * 32 + q * 8;
        float4 x = *(const float4*)sp;
        float4 y = *(const float4*)(sp + 4);
        bf16x8 o;
        o[0] = (short)f2bf(x.x); o[1] = (short)f2bf(x.y);
        o[2] = (short)f2bf(x.z); o[3] = (short)f2bf(x.w);
        o[4] = (short)f2bf(y.x); o[5] = (short)f2bf(y.y);
        o[6] = (short)f2bf(y.z); o[7] = (short)f2bf(y.w);
        *(bf16x8*)(dst + (size_t)chunk * 8) = o;
    }
}

// ---------------------------------------------------------------------------
// Fat kernel kAP (r18 = r14 exact + s_setprio around MFMA clusters).
// r14 = best measured (115.9 us). nchunk dose-response: 14->86, 28->89,
// 49->97 us => balance lever null, 14 optimal. setprio: co-resident kA
// (long loop) and kP (short burst) blocks are at different phases ->
// heterogeneous-wave regime where T5 measured +4-7%.
// ---------------------------------------------------------------------------
__global__ __launch_bounds__(512, 1)
void kAP(const float* __restrict__ key, const unsigned short* __restrict__ wfA,
         const float* __restrict__ gmaA, const float* __restrict__ btaA,
         const float* __restrict__ muA, const float* __restrict__ varA,
         float* __restrict__ part, float* __restrict__ ssqp,
         const float* __restrict__ query, const unsigned short* __restrict__ wfP,
         const float* __restrict__ gmaP, const float* __restrict__ btaP,
         const float* __restrict__ muP, const float* __restrict__ varP,
         unsigned short* __restrict__ a2T) {
    extern __shared__ char smem[];
    const int id = blockIdx.x;
    const int nA = NCHUNK * NB;
    const int tid = threadIdx.x;
    const int w = tid >> 6;
    const int lane = tid & 63;
    const int q = lane >> 4;
    const int r = lane & 15;
    const f32x4 fz = {0.f, 0.f, 0.f, 0.f};

    if (id < nA) {
        // ================= kA body =================
        unsigned short* Knc = (unsigned short*)smem;                 // [32][520] swz
        unsigned short* Kcn = (unsigned short*)(smem + 33280);       // [512][40]
        unsigned short* A1  = (unsigned short*)(smem + 74240);       // [64][40]
        float* sc = (float*)(smem + 79360);
        float* sh = sc + NL;

        const int chunk = id % NCHUNK;
        const int b     = id / NCHUNK;
        const int n0    = chunk * (NSUB * NTA);

        if (tid < NL) {
            float s = gmaA[tid] * rsqrtf(varA[tid] + 1e-5f);
            sc[tid] = s;
            sh[tid] = btaA[tid] - muA[tid] * s;
        }

        const int l0  = (w & 3) * 16;
        const int nc0 = (w >> 2) * 16;
        const int c0  = w * 64;
        const int na = nc0 + r;
        const int ga = (na >> 2) & 7;
        const unsigned short* wfp = wfA + ((size_t)((w & 3) * 1024 + q * 16 + r)) * 8;

        const int i4  = tid & 7;
        const int cb0 = tid >> 3;
        const float* kpb = key + (size_t)b * NC * NN + n0;

        // prefetch: RAW float4 (no conversion between loads)
        float4 prv[8];
        #pragma unroll
        for (int p = 0; p < 8; p++)
            prv[p] = *(const float4*)(kpb + (size_t)(cb0 + 64 * p) * NN + i4 * 4);

        f32x4 acc2[4][4];
        #pragma unroll
        for (int fm = 0; fm < 4; fm++)
            #pragma unroll
            for (int fc = 0; fc < 4; fc++) acc2[fm][fc] = fz;
        float s_acc = 0.f;

        for (int s = 0; s < NSUB; s++) {
            __syncthreads();

            // ---- convert + write prefetched sub-tile into both layouts ----
            #pragma unroll
            for (int p = 0; p < 8; p++) {
                int c = cb0 + 64 * p;
                uint2 pk;
                pk.x = (uint32_t)f2bf(prv[p].x) | ((uint32_t)f2bf(prv[p].y) << 16);
                pk.y = (uint32_t)f2bf(prv[p].z) | ((uint32_t)f2bf(prv[p].w) << 16);
                *(uint2*)&Kcn[c * 40 + i4 * 4] = pk;
                int cs = (((c >> 3) ^ i4) << 3) | (c & 7);
                int j = i4 * 4;
                Knc[(j + 0) * 520 + cs] = (unsigned short)(pk.x);
                Knc[(j + 1) * 520 + cs] = (unsigned short)(pk.x >> 16);
                Knc[(j + 2) * 520 + cs] = (unsigned short)(pk.y);
                Knc[(j + 3) * 520 + cs] = (unsigned short)(pk.y >> 16);
            }
            __syncthreads();

            // ---- prefetch NEXT sub-tile (pure loads, stay outstanding) ----
            if (s + 1 < NSUB) {
                const float* kp = kpb + (s + 1) * NTA;
                #pragma unroll
                for (int p = 0; p < 8; p++)
                    prv[p] = *(const float4*)(kp + (size_t)(cb0 + 64 * p) * NN + i4 * 4);
            }

            // GEMM1 (swapped): lane holds l=l0+r, n = nc0 + q*4 + i
            {
                f32x4 acc0 = fz;
                __builtin_amdgcn_s_setprio(1);
                #pragma unroll
                for (int it = 0; it < 16; it++) {
                    bf16x8 af = *(const bf16x8*)&wfp[it * 512];
                    bf16x8 b0 = *(const bf16x8*)&Knc[na * 520 + (((it * 4 + q) ^ ga) << 3)];
                    acc0 = __builtin_amdgcn_mfma_f32_16x16x32_bf16(b0, af, acc0, 0, 0, 0);
                }
                __builtin_amdgcn_s_setprio(0);
                const int l = l0 + r;
                const float scl = sc[l], shf = sh[l];
                ushort4 t;
                float v0 = fmaxf(acc0[0] * scl + shf, 0.f);
                float v1 = fmaxf(acc0[1] * scl + shf, 0.f);
                float v2 = fmaxf(acc0[2] * scl + shf, 0.f);
                float v3 = fmaxf(acc0[3] * scl + shf, 0.f);
                t.x = f2bf(v0); t.y = f2bf(v1); t.z = f2bf(v2); t.w = f2bf(v3);
                s_acc += v0 * v0 + v1 * v1 + v2 * v2 + v3 * v3;
                *(ushort4*)&A1[l * 40 + nc0 + q * 4] = t;
            }
            __syncthreads();

            // GEMM2 (swapped): lane holds c = c0+fc*16+q*4+i (4 contiguous)
            {
                bf16x8 a[4];
                #pragma unroll
                for (int fm = 0; fm < 4; fm++)
                    a[fm] = *(const bf16x8*)&A1[(fm * 16 + r) * 40 + q * 8];
                __builtin_amdgcn_s_setprio(1);
                #pragma unroll
                for (int fc = 0; fc < 4; fc++) {
                    bf16x8 bb = *(const bf16x8*)&Kcn[(c0 + fc * 16 + r) * 40 + q * 8];
                    #pragma unroll
                    for (int fm = 0; fm < 4; fm++)
                        acc2[fm][fc] = __builtin_amdgcn_mfma_f32_16x16x32_bf16(bb, a[fm], acc2[fm][fc], 0, 0, 0);
                }
                __builtin_amdgcn_s_setprio(0);
            }
        }

        {
            float s = s_acc;
            s += __shfl_xor(s, 16);
            s += __shfl_xor(s, 32);
            float* sp = ssqp + (((size_t)(chunk * NB + b) * 2 + (w >> 2))) * NL;
            if (lane < 16) sp[l0 + lane] = s;
        }

        // part in REGISTER ORDER: each store-inst = 1 KB contiguous.
        float* wp2 = part + ((size_t)(chunk * NB + b) * 8 + w) * 4096 + lane * 4;
        #pragma unroll
        for (int fm = 0; fm < 4; fm++)
            #pragma unroll
            for (int fc = 0; fc < 4; fc++)
                *(f32x4*)(wp2 + (fm * 4 + fc) * 256) = acc2[fm][fc];
    } else {
        // ================= kP body =================
        unsigned short* Qnc = (unsigned short*)smem;               // [32][520] swz
        unsigned short* A2  = (unsigned short*)(smem + 33280);     // [32][72]
        float* ssn = (float*)(smem + 33280 + 4608);                // [32]
        float* sc = ssn + 32;
        float* sh = sc + 64;

        const int pid = id - nA;
        const int b   = pid / NTILES32;
        const int n0  = (pid % NTILES32) * NTA;

        if (tid < 64) {
            float s = gmaP[tid] * rsqrtf(varP[tid] + 1e-5f);
            sc[tid] = s;
            sh[tid] = btaP[tid] - muP[tid] * s;
        }
        if (tid < 32) ssn[tid] = 0.f;

        const int i4  = tid & 7;
        const int cb0 = tid >> 3;
        const float* qp = query + (size_t)b * NC * NN + n0;
        float4 qv[8];
        #pragma unroll
        for (int p = 0; p < 8; p++)
            qv[p] = *(const float4*)(qp + (size_t)(cb0 + 64 * p) * NN + i4 * 4);
        #pragma unroll
        for (int p = 0; p < 8; p++) {
            int c = cb0 + 64 * p;
            int cs = (((c >> 3) ^ i4) << 3) | (c & 7);
            int j = i4 * 4;
            Qnc[(j + 0) * 520 + cs] = f2bf(qv[p].x);
            Qnc[(j + 1) * 520 + cs] = f2bf(qv[p].y);
            Qnc[(j + 2) * 520 + cs] = f2bf(qv[p].z);
            Qnc[(j + 3) * 520 + cs] = f2bf(qv[p].w);
        }
        __syncthreads();

        const int l0 = (w & 3) * 16, nc0 = (w >> 2) * 16;
        const int na = nc0 + r;
        const int ga = (na >> 2) & 7;
        const unsigned short* wfp = wfP + ((size_t)((w & 3) * 1024 + q * 16 + r)) * 8;

        f32x4 acc0 = fz;
        __builtin_amdgcn_s_setprio(1);
        #pragma unroll
        for (int it = 0; it < 16; it++) {
            bf16x8 af = *(const bf16x8*)&wfp[it * 512];
            bf16x8 b0 = *(const bf16x8*)&Qnc[na * 520 + (((it * 4 + q) ^ ga) << 3)];
            acc0 = __builtin_amdgcn_mfma_f32_16x16x32_bf16(af, b0, acc0, 0, 0, 0);
        }
        __builtin_amdgcn_s_setprio(0);

        float s0 = 0.f;
        {
            unsigned short t0[4];
            #pragma unroll
            for (int i = 0; i < 4; i++) {
                int l = l0 + q * 4 + i;
                float v0 = fmaxf(acc0[i] * sc[l] + sh[l], 0.f);
                t0[i] = f2bf(v0);
                s0 += v0 * v0;
            }
            *(ushort4*)&A2[na * 72 + l0 + 4 * q] = make_ushort4(t0[0], t0[1], t0[2], t0[3]);
        }

        s0 += __shfl_xor(s0, 16);
        s0 += __shfl_xor(s0, 32);
        if (lane < 16) atomicAdd(&ssn[na], s0);
        __syncthreads();

        if (tid < 256) {
            int row = tid >> 3, ch = tid & 7;
            float inv = 1.f / fmaxf(sqrtf(ssn[row]), 1e-12f);
            bf16x8 x = *(const bf16x8*)&A2[row * 72 + ch * 8];
            bf16x8 o;
            #pragma unroll
            for (int k = 0; k < 8; k++)
                o[k] = (short)f2bf(bf2f((unsigned short)x[k]) * inv);
            *(bf16x8*)&a2T[((size_t)b * NN + n0 + row) * 64 + ch * 8] = o;
        }
    }
}

// ---------------------------------------------------------------------------
// Kernel R: inverse-map reduce of register-ordered part.
// ---------------------------------------------------------------------------
__global__ __launch_bounds__(256)
void kR(const float* __restrict__ part, float* __restrict__ latu) {
    int gid = blockIdx.x * 256 + threadIdx.x;   // 0..65535
    int lane = gid & 63;
    int fc = (gid >> 6) & 3;
    int fm = (gid >> 8) & 3;
    int w  = (gid >> 10) & 7;
    int b  = gid >> 13;
    int q = lane >> 4, r = lane & 15;

    const float* src = part + ((size_t)(b * 8 + w) * 16 + fm * 4 + fc) * 256 + lane * 4;
    f32x4 acc = {0.f, 0.f, 0.f, 0.f};
    for (int ch = 0; ch < NCHUNK; ch++) {
        f32x4 v = *(const f32x4*)(src + (size_t)ch * (NB * 8 * 4096));
        acc += v;
    }
    float* dst = latu + ((size_t)(b * 64 + fm * 16 + r)) * NC + w * 64 + fc * 16 + q * 4;
    *(f32x4*)dst = acc;
}

// ---------------------------------------------------------------------------
// Kernel B (one block per b): ssq reduce; latent norm; aff softmax; latent2.
// ---------------------------------------------------------------------------
__global__ __launch_bounds__(256, 1)
void kB(const float* __restrict__ latu, const float* __restrict__ ssqp,
        unsigned short* __restrict__ lat2T) {
    extern __shared__ char smem[];
    unsigned short* Lb = (unsigned short*)smem;             // [64][520]
    unsigned short* Lt = (unsigned short*)(smem + 66560);   // [512][72]
    float* aff = (float*)(smem + 140288);                   // [64][68]
    float* inv_nl = (float*)(smem + 157696);
    float* s_c = inv_nl + 64;

    const int tid = threadIdx.x;
    const int b = blockIdx.x;

    if (tid < 64) {
        float s = 0.f;
        for (int ch = 0; ch < NCHUNK; ch++) {
            size_t base = (((size_t)ch * NB + b) * 2) * NL + tid;
            s += ssqp[base] + ssqp[base + NL];
        }
        inv_nl[tid] = 1.f / fmaxf(sqrtf(s), 1e-12f);
    }
    __syncthreads();

    const float* lu = latu + (size_t)b * NL * NC;
    for (int idx = tid; idx < NL * (NC / 4); idx += 256) {
        int l = idx >> 7;
        int c = (idx & 127) << 2;
        float4 v = *(const float4*)(lu + l * NC + c);
        float inv = inv_nl[l];
        unsigned short b0 = f2bf(v.x * inv), b1 = f2bf(v.y * inv);
        unsigned short b2 = f2bf(v.z * inv), b3 = f2bf(v.w * inv);
        uint32_t* d = (uint32_t*)&Lb[l * 520 + c];
        d[0] = (uint32_t)b0 | ((uint32_t)b1 << 16);
        d[1] = (uint32_t)b2 | ((uint32_t)b3 << 16);
        Lt[(c + 0) * 72 + l] = b0;
        Lt[(c + 1) * 72 + l] = b1;
        Lt[(c + 2) * 72 + l] = b2;
        Lt[(c + 3) * 72 + l] = b3;
    }
    __syncthreads();

    {
        int l = tid >> 2, p = tid & 3;
        float s = 0.f;
        for (int c = p * 128; c < p * 128 + 128; c += 4) {
            const unsigned short* d = &Lb[l * 520 + c];
            float v0 = bf2f(d[0]), v1 = bf2f(d[1]), v2 = bf2f(d[2]), v3 = bf2f(d[3]);
            s += v0 * v0 + v1 * v1 + v2 * v2 + v3 * v3;
        }
        s += __shfl_xor(s, 1);
        s += __shfl_xor(s, 2);
        if (p == 0) s_c[l] = 1.f / fmaxf(sqrtf(s), 1e-12f);
    }
    __syncthreads();

    const int w = tid >> 6, lane = tid & 63, q = lane >> 4, r = lane & 15;
    const f32x4 fz = {0.f, 0.f, 0.f, 0.f};

    {
        f32x4 g[4];
        #pragma unroll
        for (int fm = 0; fm < 4; fm++) g[fm] = fz;
        for (int kc = 0; kc < NC; kc += 32) {
            bf16x8 a = *(const bf16x8*)&Lb[(w * 16 + r) * 520 + kc + q * 8];
            #pragma unroll
            for (int fm = 0; fm < 4; fm++) {
                bf16x8 bb = *(const bf16x8*)&Lb[(fm * 16 + r) * 520 + kc + q * 8];
                g[fm] = __builtin_amdgcn_mfma_f32_16x16x32_bf16(a, bb, g[fm], 0, 0, 0);
            }
        }
        #pragma unroll
        for (int fm = 0; fm < 4; fm++)
            #pragma unroll
            for (int i = 0; i < 4; i++) {
                int l = w * 16 + q * 4 + i;
                int m = fm * 16 + r;
                aff[l * 68 + m] = g[fm][i] * s_c[l] * s_c[m];
            }
    }
    __syncthreads();

    {
        int l = tid >> 2, p = tid & 3;
        float e[16];
        float mx = -1e30f;
        #pragma unroll
        for (int k = 0; k < 16; k++) mx = fmaxf(mx, aff[l * 68 + p * 16 + k]);
        mx = fmaxf(mx, __shfl_xor(mx, 1));
        mx = fmaxf(mx, __shfl_xor(mx, 2));
        float s = 0.f;
        #pragma unroll
        for (int k = 0; k < 16; k++) { e[k] = __expf(aff[l * 68 + p * 16 + k] - mx); s += e[k]; }
        s += __shfl_xor(s, 1);
        s += __shfl_xor(s, 2);
        float invs = 1.f / s;
        __syncthreads();
        #pragma unroll
        for (int k = 0; k < 16; k++) aff[l * 68 + p * 16 + k] = e[k] * invs;
    }
    __syncthreads();

    {
        f32x4 acc[4][8];
        #pragma unroll
        for (int fm = 0; fm < 4; fm++)
            #pragma unroll
            for (int fc = 0; fc < 8; fc++) acc[fm][fc] = fz;
        #pragma unroll
        for (int km = 0; km < 64; km += 32) {
            bf16x8 a[4];
            #pragma unroll
            for (int fm = 0; fm < 4; fm++) {
                const float* ap = &aff[(fm * 16 + r) * 68 + km + q * 8];
                float4 x = *(const float4*)ap;
                float4 y = *(const float4*)(ap + 4);
                bf16x8 t;
                t[0] = (short)f2bf(x.x); t[1] = (short)f2bf(x.y);
                t[2] = (short)f2bf(x.z); t[3] = (short)f2bf(x.w);
                t[4] = (short)f2bf(y.x); t[5] = (short)f2bf(y.y);
                t[6] = (short)f2bf(y.z); t[7] = (short)f2bf(y.w);
                a[fm] = t;
            }
            #pragma unroll
            for (int fc = 0; fc < 8; fc++) {
                bf16x8 bb = *(const bf16x8*)&Lt[(w * 128 + fc * 16 + r) * 72 + km + q * 8];
                #pragma unroll
                for (int fm = 0; fm < 4; fm++)
                    acc[fm][fc] = __builtin_amdgcn_mfma_f32_16x16x32_bf16(a[fm], bb, acc[fm][fc], 0, 0, 0);
            }
        }
        unsigned short* out = lat2T + (size_t)b * NC * NL;
        #pragma unroll
        for (int fm = 0; fm < 4; fm++)
            #pragma unroll
            for (int fc = 0; fc < 8; fc++)
                #pragma unroll
                for (int i = 0; i < 4; i++) {
                    int l = fm * 16 + q * 4 + i;
                    int c = w * 128 + fc * 16 + r;
                    out[c * 64 + l] = f2bf(acc[fm][fc][i]);
                }
    }
}

// ---------------------------------------------------------------------------
// Kernel C3: operand-swapped + LDS bounce (4-row x 256 B contiguous stores)
// ---------------------------------------------------------------------------
__global__ __launch_bounds__(256, 4)
void kC3(const unsigned short* __restrict__ a2T,
         const unsigned short* __restrict__ lat2T, float* __restrict__ out) {
    __shared__ unsigned short At[64 * 72];   // [n][72 l]
    __shared__ float Bnc[4][16][68];         // per-wave [c16][n64+4]

    const int tid = threadIdx.x;
    const int b = blockIdx.y;
    const int n0 = blockIdx.x * NT;

    const unsigned short* src = a2T + ((size_t)b * NN + n0) * 64;
    #pragma unroll
    for (int k = 0; k < 2; k++) {
        int idx = tid + k * 256;
        int row = idx >> 3, ch = idx & 7;
        *(uint4*)&At[row * 72 + ch * 8] = *(const uint4*)&src[row * 64 + ch * 8];
    }
    __syncthreads();

    const int w = tid >> 6, lane = tid & 63, q = lane >> 4, r = lane & 15;
    const f32x4 fz = {0.f, 0.f, 0.f, 0.f};
    const unsigned short* Ab = lat2T + (size_t)b * NC * NL;
    float* op = out + (size_t)b * NC * NN + n0;

    #pragma unroll
    for (int half = 0; half < 2; half++) {
        int cb = w * 128 + half * 64;
        f32x4 acc[4][4];
        #pragma unroll
        for (int fm = 0; fm < 4; fm++)
            #pragma unroll
            for (int fn = 0; fn < 4; fn++) acc[fm][fn] = fz;
        #pragma unroll
        for (int kl = 0; kl < 64; kl += 32) {
            bf16x8 a[4];
            #pragma unroll
            for (int fm = 0; fm < 4; fm++)
                a[fm] = *(const bf16x8*)&Ab[(size_t)(cb + fm * 16 + r) * 64 + kl + q * 8];
            #pragma unroll
            for (int fn = 0; fn < 4; fn++) {
                bf16x8 bb = *(const bf16x8*)&At[(fn * 16 + r) * 72 + kl + q * 8];
                #pragma unroll
                for (int fm = 0; fm < 4; fm++)
                    acc[fm][fn] = __builtin_amdgcn_mfma_f32_16x16x32_bf16(bb, a[fm], acc[fm][fn], 0, 0, 0);
            }
        }
        #pragma unroll
        for (int fm = 0; fm < 4; fm++) {
            #pragma unroll
            for (int fn = 0; fn < 4; fn++)
                *(f32x4*)&Bnc[w][r][fn * 16 + q * 4] = acc[fm][fn];
            #pragma unroll
            for (int rb = 0; rb < 4; rb++) {
                int crow = rb * 4 + (lane >> 4);
                f32x4 v = *(const f32x4*)&Bnc[w][crow][(lane & 15) * 4];
                *(f32x4*)(op + (size_t)(cb + fm * 16 + crow) * NN + (lane & 15) * 4) = v;
            }
        }
    }
}

// ---------------------------------------------------------------------------
extern "C" void kernel_launch(void* const* d_in, const int* in_sizes, int n_in,
                              void* d_out, int out_size, void* d_ws, size_t ws_size,
                              hipStream_t stream) {
    (void)in_sizes; (void)n_in; (void)out_size; (void)ws_size;
    const float* query = (const float*)d_in[0];
    const float* key   = (const float*)d_in[1];
    const float* phi_w = (const float*)d_in[2];
    const float* phi_g = (const float*)d_in[3];
    const float* phi_b = (const float*)d_in[4];
    const float* phi_m = (const float*)d_in[5];
    const float* phi_v = (const float*)d_in[6];
    const float* php_w = (const float*)d_in[7];
    const float* php_g = (const float*)d_in[8];
    const float* php_b = (const float*)d_in[9];
    const float* php_m = (const float*)d_in[10];
    const float* php_v = (const float*)d_in[11];
    float* out = (float*)d_out;

    char* ws = (char*)d_ws;
    size_t off = 0;
    float* part = (float*)(ws + off);           off += (size_t)NCHUNK * NB * NL * NC * 4;  // 14.68 MB
    float* ssqp = (float*)(ws + off);           off += (size_t)NCHUNK * NB * 2 * NL * 4;
    float* latu = (float*)(ws + off);           off += 1048576;
    unsigned short* lat2T = (unsigned short*)(ws + off); off += 524288;
    unsigned short* a2T   = (unsigned short*)(ws + off); off += 6422528;
    unsigned short* wfA   = (unsigned short*)(ws + off); off += 65536;
    unsigned short* wfP   = (unsigned short*)(ws + off); off += 65536;

    (void)hipFuncSetAttribute((const void*)kAP, hipFuncAttributeMaxDynamicSharedMemorySize, 79872);
    (void)hipFuncSetAttribute((const void*)kB, hipFuncAttributeMaxDynamicSharedMemorySize, 158208);

    kW<<<dim3(2), 512, 0, stream>>>(phi_w, php_w, wfA, wfP);
    int nblocks = NCHUNK * NB + NTILES32 * NB;
    kAP<<<dim3(nblocks), 512, 79872, stream>>>(key, wfA, phi_g, phi_b, phi_m, phi_v,
                                               part, ssqp,
                                               query, wfP, php_g, php_b, php_m, php_v, a2T);
    kR<<<dim3(256), 256, 0, stream>>>(part, latu);
    kB<<<dim3(NB), 256, 158208, stream>>>(latu, ssqp, lat2T);
    kC3<<<dim3(NTILES, NB), 256, 0, stream>>>(a2T, lat2T, out);
}